// Round 5
// baseline (404.659 us; speedup 1.0000x reference)
//
#include <hip/hip_runtime.h>
#include <math.h>

// Keep box arithmetic bit-identical to numpy fp32 (no fma contraction):
// matching decisions (iou > 0.5, argmax) must not flip.
#pragma clang fp contract(off)

#define BB 64
#define AA 8732
#define CC 81
#define GG 32
#define AB (BB*AA)          // 558848
#define A_BLOCKS 35         // ceil(8732/256)
#define KA1_BLOCKS (BB*A_BLOCKS)   // 2240
#define KA2_BLOCKS (BB*GG/4)       // 512
#define KC_GRID 768         // 3 blocks/CU * 256 CUs (LDS 41472 B -> 3 blocks/CU)
#define KC_WAVES (KC_GRID*4)       // 3072
#define WTILES (AB/32)      // 17464 wave-tiles of 32 anchors

// ---- workspace layout (bytes) ----
// [0,8192)           bestp  u32[B*G] best anchor per gt (written fully by kA2 role)
// [16640,575488)     bestg  u8[B*A]
// [575488,1134336)   label  u8[B*A]
// [1134336,3369728)  cls_l  f32[B*A]
// [3369728,3369984)  num_pos int[64]
// [3369984,3370496)  loc_sum double[64]
// [3370496,3371008)  btot   double[64]

// ---------------- Kernel A: both matchings in one dispatch ----------------
// blocks [0, 2240): per-anchor best gt (thread per anchor).
// blocks [2240, 2752): per-gt best anchor (one wave per (b,g)).
// iou compare via cross-multiplication: iou1>iou2 <=> i1*u2 > i2*u1 (all >0);
// threshold iou>0.5 <=> 2*i > u. No division, no u64 keys, no atomics.
__global__ __launch_bounds__(256) void kA_match(const float* __restrict__ anchors,
    const float* __restrict__ gt_boxes,
    unsigned char* __restrict__ bestg, unsigned int* __restrict__ bestp)
{
    int tid = threadIdx.x;
    if (blockIdx.x < KA1_BLOCKS) {
        int blk = blockIdx.x;
        int b = blk / A_BLOCKS, ca = blk % A_BLOCKS;
        int a = ca * 256 + tid;
        __shared__ float4 gco[GG];             // x1,y1,x2,y2
        __shared__ float gar[GG];
        if (tid < GG) {
            float4 gb = ((const float4*)gt_boxes)[b * GG + tid];
            float x1 = gb.x - gb.z / 2.0f, y1 = gb.y - gb.w / 2.0f;
            float x2 = gb.x + gb.z / 2.0f, y2 = gb.y + gb.w / 2.0f;
            gco[tid] = make_float4(x1, y1, x2, y2);
            gar[tid] = (x2 - x1) * (y2 - y1);  // same rounding as reference
        }
        __syncthreads();
        if (a >= AA) return;

        float4 an = ((const float4*)anchors)[a];
        float ax1 = an.x - an.z / 2.0f, ay1 = an.y - an.w / 2.0f;
        float ax2 = an.x + an.z / 2.0f, ay2 = an.y + an.w / 2.0f;
        float aar = (ax2 - ax1) * (ay2 - ay1);
        float bi = -1.0f, bu = 1.0f; int bgi = 0;  // first compare always takes g=0
#pragma unroll
        for (int g = 0; g < GG; ++g) {
            float4 c = gco[g];
            float ltx = fmaxf(c.x, ax1), lty = fmaxf(c.y, ay1);
            float rbx = fminf(c.z, ax2), rby = fminf(c.w, ay2);
            float w = fmaxf(rbx - ltx, 0.0f), h = fmaxf(rby - lty, 0.0f);
            float inter = w * h;
            float uni = gar[g] + aar - inter;
            if (inter * bu > bi * uni) { bi = inter; bu = uni; bgi = g; }  // strict >: first max
        }
        bestg[b * AA + a] = (2.0f * bi > bu) ? (unsigned char)bgi : (unsigned char)0xFF;
    } else {
        int wv = tid >> 6, lane = tid & 63;
        int pair = (blockIdx.x - KA1_BLOCKS) * 4 + wv;  // 0..2047
        int b = pair >> 5, g = pair & 31;
        float4 gb = ((const float4*)gt_boxes)[b * GG + g];
        float gx1 = gb.x - gb.z / 2.0f, gy1 = gb.y - gb.w / 2.0f;
        float gx2 = gb.x + gb.z / 2.0f, gy2 = gb.y + gb.w / 2.0f;
        float gar = (gx2 - gx1) * (gy2 - gy1);

        float bi = -1.0f, bu = 1.0f; int ba = 0;
        for (int a = lane; a < AA; a += 64) {
            float4 an = ((const float4*)anchors)[a];
            float ax1 = an.x - an.z / 2.0f, ay1 = an.y - an.w / 2.0f;
            float ax2 = an.x + an.z / 2.0f, ay2 = an.y + an.w / 2.0f;
            float aar = (ax2 - ax1) * (ay2 - ay1);
            float ltx = fmaxf(gx1, ax1), lty = fmaxf(gy1, ay1);
            float rbx = fminf(gx2, ax2), rby = fminf(gy2, ay2);
            float w = fmaxf(rbx - ltx, 0.0f), h = fmaxf(rby - lty, 0.0f);
            float inter = w * h;
            float uni = gar + aar - inter;
            if (inter * bu > bi * uni) { bi = inter; bu = uni; ba = a; }  // smallest a in stream
        }
        // wave butterfly-reduce, lexicographic (iou desc, a asc)
#pragma unroll
        for (int off = 32; off > 0; off >>= 1) {
            float oi = __shfl_down(bi, off);
            float ou = __shfl_down(bu, off);
            int   oa = __shfl_down(ba, off);
            float p1 = oi * bu, p2 = bi * ou;
            bool take = (p1 > p2) || ((p1 == p2) && (oa < ba));
            if (take) { bi = oi; bu = ou; ba = oa; }
        }
        if (lane == 0) bestp[pair] = (unsigned int)ba;
    }
}

// ---------------- Kernel B: forced override (last g wins), labels, loc loss ----------------
__global__ __launch_bounds__(256) void kB_finalize(const float* __restrict__ anchors,
    const float* __restrict__ gt_boxes, const int* __restrict__ gt_labels,
    const float* __restrict__ loc_pred,
    const unsigned char* __restrict__ bestg,
    const unsigned int* __restrict__ bestp,
    unsigned char* __restrict__ label_out,
    int* __restrict__ num_pos, double* __restrict__ loc_sum)
{
    int b = blockIdx.x, tid = threadIdx.x;
    __shared__ int forced[AA];                 // 34928 B
    __shared__ float gcx[GG], gcy[GG], gw[GG], gh[GG];
    __shared__ int glab[GG];
    __shared__ double red_d[256];
    __shared__ int red_i[256];

    for (int i = tid; i < AA; i += 256) forced[i] = -1;
    if (tid < GG) {
        float4 gb = ((const float4*)gt_boxes)[b * GG + tid];
        gcx[tid] = gb.x; gcy[tid] = gb.y; gw[tid] = gb.z; gh[tid] = gb.w;
        glab[tid] = gt_labels[b * GG + tid];
    }
    __syncthreads();
    if (tid < GG) {
        int besta = (int)bestp[b * GG + tid];
        atomicMax(&forced[besta], tid);        // duplicate anchors: largest g = last write wins
    }
    __syncthreads();

    double lsum = 0.0; int pcount = 0;
    for (int a = tid; a < AA; a += 256) {
        int gf = forced[a];
        int gsel;
        if (gf >= 0) gsel = gf;
        else {
            unsigned char bg = bestg[b * AA + a];
            gsel = (bg == 0xFF) ? -1 : (int)bg;
        }
        int lab = 0;
        if (gsel >= 0) {
            lab = glab[gsel];                  // labels in 1..C-1 -> always positive
            float4 an = ((const float4*)anchors)[a];
            float e0 = (gcx[gsel] - an.x) / an.z;
            float e1 = (gcy[gsel] - an.y) / an.w;
            float e2 = logf(gw[gsel]) - logf(an.z);
            float e3 = logf(gh[gsel]) - logf(an.w);
            float4 lp = ((const float4*)loc_pred)[b * AA + a];
            float d0 = lp.x - e0, d1 = lp.y - e1, d2 = lp.z - e2, d3 = lp.w - e3;
            float t = 0.0f, ad;
            ad = fabsf(d0); t += (ad < 1.0f) ? 0.5f * d0 * d0 : ad - 0.5f;
            ad = fabsf(d1); t += (ad < 1.0f) ? 0.5f * d1 * d1 : ad - 0.5f;
            ad = fabsf(d2); t += (ad < 1.0f) ? 0.5f * d2 * d2 : ad - 0.5f;
            ad = fabsf(d3); t += (ad < 1.0f) ? 0.5f * d3 * d3 : ad - 0.5f;
            lsum += (double)t;
            pcount++;
        }
        label_out[b * AA + a] = (unsigned char)lab;
    }
    red_d[tid] = lsum; red_i[tid] = pcount;
    __syncthreads();
    for (int s = 128; s > 0; s >>= 1) {
        if (tid < s) { red_d[tid] += red_d[tid + s]; red_i[tid] += red_i[tid + s]; }
        __syncthreads();
    }
    if (tid == 0) { num_pos[b] = red_i[0]; loc_sum[b] = red_d[0]; }
}

// ---------------- Kernel C v4: barrier-free wave-private streaming pipelines ----------------
// 768 blocks (3/CU), 4 waves/block, each wave owns a private 32-anchor LDS tile
// (10368 B) and register-prefetches its next tile. ZERO __syncthreads in the
// loop: the compiler emits fine-grained vmcnt/lgkmcnt waits (no barrier-forced
// vmcnt(0) drain), so prefetch loads stay in flight across compute. Cross-lane
// LDS reuse within one wave is safe without a barrier (lockstep wave exec,
// in-order DS unit).
__global__ __launch_bounds__(256) void kC_conf(const float* __restrict__ conf,
    float* __restrict__ cls_l)
{
    __shared__ float buf[4][2592];             // 4 waves x (32 rows x 81), 41472 B
    int tid = threadIdx.x;
    int wv = tid >> 6, lane = tid & 63;
    float* wbuf = buf[wv];
    const float4* __restrict__ src = (const float4*)conf;
    int W = blockIdx.x * 4 + wv;               // wave id, 0..3071

    // prefetch first tile into registers: 648 float4 per tile = 10/lane + 8 extra
    float4 r[10]; float4 rx;
    {
        size_t base = (size_t)W * 648;
#pragma unroll
        for (int k = 0; k < 10; ++k) r[k] = src[base + lane + k * 64];
        if (lane < 8) rx = src[base + 640 + lane];
    }
    int row = lane >> 1, h = lane & 1;         // 2 lanes per anchor row
    const float* myrow = wbuf + row * 81 + h * 40;
    for (int wt = W; wt < WTILES; ) {
        float4* d4 = (float4*)wbuf;
#pragma unroll
        for (int k = 0; k < 10; ++k) d4[lane + k * 64] = r[k];
        if (lane < 8) d4[640 + lane] = rx;
        int wn = wt + KC_WAVES;
        if (wn < WTILES) {                     // issue next tile's loads now
            size_t nb = (size_t)wn * 648;
#pragma unroll
            for (int k = 0; k < 10; ++k) r[k] = src[nb + lane + k * 64];
            if (lane < 8) rx = src[nb + 640 + lane];
        }
        // lane sums its 40 (h=0: classes 0..39) or 41 (h=1: 40..80) classes
        float s = 0.0f;
#pragma unroll
        for (int c = 0; c < 40; ++c) s += __expf(myrow[c]);
        if (h) s += __expf(myrow[40]);         // class 80
        s += __shfl_xor(s, 1);
        if (h == 0) {
            float lse = __logf(s);
            cls_l[wt * 32 + row] = lse - myrow[0];  // h=0: myrow[0] is class 0
        }
        wt = wn;
    }
}

// ---------------- Kernel D: per-batch radix-select top-k + positive CE + batch total ----------------
__global__ __launch_bounds__(256) void kD_select(const float* __restrict__ cls_l,
    const unsigned char* __restrict__ label, const float* __restrict__ conf,
    const int* __restrict__ num_pos, const double* __restrict__ loc_sum,
    double* __restrict__ btot)
{
    int b = blockIdx.x, tid = threadIdx.x;
    __shared__ unsigned int cl[AA];            // 34928 B (values clamped >= 0 -> bits monotone)
    __shared__ unsigned int hist[256];
    __shared__ unsigned int sh_prefix, sh_remaining;
    __shared__ double red_d[256];
    __shared__ unsigned int red_u[256];
    __shared__ double sh_pos;

    const float* src = cls_l + b * AA;
    const unsigned char* lb = label + b * AA;
    double pc = 0.0;
    for (int i = tid; i < AA; i += 256) {
        int lab = lb[i];
        float v = fmaxf(src[i], 0.0f);         // guard tiny negative lse-row0 rounding
        if (lab > 0) {
            size_t rowb = (size_t)(b * AA + i) * 81;
            pc += (double)(src[i] + conf[rowb] - conf[rowb + lab]);
            cl[i] = 0u;                        // positives excluded from neg mining
        } else {
            cl[i] = __float_as_uint(v);
        }
    }
    red_d[tid] = pc;
    __syncthreads();
    for (int s = 128; s > 0; s >>= 1) {
        if (tid < s) red_d[tid] += red_d[tid + s];
        __syncthreads();
    }
    if (tid == 0) sh_pos = red_d[0];

    int np_ = num_pos[b];
    int k = min(3 * np_, AA - 1);              // num_neg = min(3*num_pos, A-1)
    double topk = 0.0;
    int p_t_pos = 0;                           // positives inside neg_mask (tie at 0)
    if (tid == 0) { sh_prefix = 0u; sh_remaining = (unsigned int)k; }
    __syncthreads();

    if (k > 0) {
        for (int shift = 24; shift >= 0; shift -= 8) {
            hist[tid] = 0u;
            __syncthreads();
            unsigned int mask = (shift == 24) ? 0u : (0xFFFFFFFFu << (shift + 8));
            unsigned int pre = sh_prefix;
            for (int i = tid; i < AA; i += 256) {
                unsigned int u = cl[i];
                if ((u & mask) == pre) atomicAdd(&hist[(u >> shift) & 255], 1u);
            }
            __syncthreads();
            if (tid < 64) {                    // wave-parallel digit select
                int l = tid;
                unsigned int h4 = hist[4 * l] + hist[4 * l + 1]
                                + hist[4 * l + 2] + hist[4 * l + 3];
                unsigned int S = h4;           // suffix sum over lane groups
#pragma unroll
                for (int off = 1; off < 64; off <<= 1) {
                    unsigned int o = __shfl_down(S, off);
                    S += (l + off < 64) ? o : 0u;
                }
                unsigned int rem = sh_remaining;
                unsigned long long ball = __ballot(S >= rem);  // lanes 0..L set
                int L = 63 - __clzll(ball);
                if (l == L) {
                    unsigned int rem2 = rem - (S - h4);
                    unsigned int c = 0;
                    for (int dd = 4 * L + 3; dd >= 4 * L; --dd) {
                        c += hist[dd];
                        if (c >= rem2) {
                            sh_prefix = pre | ((unsigned int)dd << shift);
                            sh_remaining = rem2 - (c - hist[dd]);
                            break;
                        }
                    }
                }
            }
            __syncthreads();
        }
        unsigned int vbits = sh_prefix;
        unsigned int myc = 0; double mys = 0.0;
        for (int i = tid; i < AA; i += 256) {
            unsigned int u = cl[i];
            if (u > vbits) { myc++; mys += (double)__uint_as_float(u); }
        }
        red_u[tid] = myc; red_d[tid] = mys;
        __syncthreads();
        for (int s2 = 128; s2 > 0; s2 >>= 1) {
            if (tid < s2) { red_u[tid] += red_u[tid + s2]; red_d[tid] += red_d[tid + s2]; }
            __syncthreads();
        }
        int cnt_gt = (int)red_u[0];
        double sum_gt = red_d[0];
        topk = sum_gt + (double)(k - cnt_gt) * (double)__uint_as_float(vbits);
        if (tid == 0 && vbits == 0u) {
            int t = k - cnt_gt, c2 = 0;
            for (int i = 0; i < AA && c2 < t; ++i) {
                if (cl[i] == 0u) { c2++; if (lb[i] > 0) p_t_pos++; }
            }
        }
    }
    if (tid == 0) {
        int unsampled = AA - np_ - k + p_t_pos;
        double clsb = sh_pos + topk + (double)unsampled * (double)logf(81.0f);
        btot[b] = loc_sum[b] + clsb;
    }
}

// ---------------- Kernel E: final scalar ----------------
__global__ __launch_bounds__(64) void kE_final(const double* __restrict__ btot,
    const int* __restrict__ num_pos, float* __restrict__ out)
{
    int tid = threadIdx.x;                     // 64 = one wave
    double t = btot[tid];
    int n = num_pos[tid];
    for (int o = 32; o > 0; o >>= 1) { t += __shfl_down(t, o); n += __shfl_down(n, o); }
    if (tid == 0) out[0] = (float)(t / (double)n);
}

extern "C" void kernel_launch(void* const* d_in, const int* in_sizes, int n_in,
                              void* d_out, int out_size, void* d_ws, size_t ws_size,
                              hipStream_t stream) {
    (void)in_sizes; (void)n_in; (void)out_size; (void)ws_size;
    const float* loc_pred  = (const float*)d_in[0];
    const float* conf_pred = (const float*)d_in[1];
    const float* anchors   = (const float*)d_in[2];
    const float* gt_boxes  = (const float*)d_in[3];
    const int*   gt_labels = (const int*)d_in[4];

    char* ws = (char*)d_ws;
    unsigned int*  bestp   = (unsigned int*)(ws + 0);    // fully written by kA2 role
    unsigned char* bestg   = (unsigned char*)(ws + 16640);
    unsigned char* label   = (unsigned char*)(ws + 575488);
    float*         cls_l   = (float*)(ws + 1134336);
    int*           num_pos = (int*)(ws + 3369728);
    double*        loc_sum = (double*)(ws + 3369984);
    double*        btot    = (double*)(ws + 3370496);

    kA_match   <<<KA1_BLOCKS + KA2_BLOCKS, 256, 0, stream>>>(anchors, gt_boxes, bestg, bestp);
    kB_finalize<<<BB,      256, 0, stream>>>(anchors, gt_boxes, gt_labels, loc_pred,
                                             bestg, bestp, label, num_pos, loc_sum);
    kC_conf    <<<KC_GRID, 256, 0, stream>>>(conf_pred, cls_l);
    kD_select  <<<BB,      256, 0, stream>>>(cls_l, label, conf_pred, num_pos, loc_sum, btot);
    kE_final   <<<1,        64, 0, stream>>>(btot, num_pos, (float*)d_out);
}

// Round 6
// 373.385 us; speedup vs baseline: 1.0838x; 1.0838x over previous
//
#include <hip/hip_runtime.h>
#include <math.h>

// Keep box arithmetic bit-identical to numpy fp32 (no fma contraction):
// matching decisions (iou > 0.5, argmax) must not flip.
#pragma clang fp contract(off)

#define BB 64
#define AA 8732
#define CC 81
#define GG 32
#define AB (BB*AA)          // 558848 rows
#define A_BLOCKS 35         // ceil(8732/256)
#define KC_BLOCKS 768
#define KA1_BLOCKS (BB*A_BLOCKS)   // 2240
#define KA2_BLOCKS (BB*GG/4)       // 512
#define KC_STRIDE (KC_BLOCKS*256)  // 196608 rows per grid-stride step

// ---- workspace layout (bytes) ----
// [0,8192)           bestp  u32[B*G] best anchor per gt (fully written by kA2 role)
// [16640,575488)     bestg  u8[B*A]
// [575488,1134336)   label  u8[B*A]
// [1134336,3369728)  cls_l  f32[B*A]
// [3369728,3369984)  num_pos int[64]
// [3369984,3370496)  loc_sum double[64]
// [3370496,3370500)  ticket u32          (zeroed by kB)
// [3370504,3370512)  btot_acc double     (zeroed by kB)
// [3370512,3370516)  np_acc int          (zeroed by kB)

// ---------------- Kernel AC: conf logsumexp stream + both matchings, one dispatch ----------------
// blocks [0,768): kC role — one lane per 81-class row, NO LDS. Lane reads 21
//   aligned float4 from (row_start & ~15B); head/tail elements masked by
//   pre = (r*81)&3. Never OOB: the tensor's last row has pre==3 exactly.
// blocks [768,3008): kA1 role — per-anchor best gt (thread per anchor).
// blocks [3008,3520): kA2 role — per-gt best anchor (one wave per (b,g)).
// iou compare by cross-multiplication: iou1>iou2 <=> i1*u2 > i2*u1 (all >0);
// threshold iou>0.5 <=> 2*i > u. No division anywhere.
__global__ __launch_bounds__(256) void kAC(const float* __restrict__ anchors,
    const float* __restrict__ gt_boxes, const float* __restrict__ conf,
    unsigned char* __restrict__ bestg, unsigned int* __restrict__ bestp,
    float* __restrict__ cls_l)
{
    int tid = threadIdx.x;
    if (blockIdx.x < KC_BLOCKS) {
        const float4* __restrict__ src4 = (const float4*)conf;
        for (int r = blockIdx.x * 256 + tid; r < AB; r += KC_STRIDE) {
            int off = r * 81;                  // max 45.3M, fits int
            int base4 = off >> 2;
            int pre = off & 3;
            float4 v[21];
#pragma unroll
            for (int j = 0; j < 21; ++j) v[j] = src4[(size_t)base4 + j];
            const float* f = (const float*)v;  // constant indices after unroll -> stays in VGPRs
            float s = 0.0f;
            s += (pre == 0) ? __expf(f[0]) : 0.0f;   // k=0 in row iff pre==0
            s += (pre <= 1) ? __expf(f[1]) : 0.0f;
            s += (pre <= 2) ? __expf(f[2]) : 0.0f;
#pragma unroll
            for (int k = 3; k <= 80; ++k) s += __expf(f[k]);   // always in row
            s += (pre >= 1) ? __expf(f[81]) : 0.0f;
            s += (pre >= 2) ? __expf(f[82]) : 0.0f;
            s += (pre == 3) ? __expf(f[83]) : 0.0f;
            float r0 = (pre == 0) ? f[0] : (pre == 1) ? f[1] : (pre == 2) ? f[2] : f[3];
            cls_l[r] = __logf(s) - r0;         // idx01=0 for negatives; kD masks positives
        }
    } else if (blockIdx.x < KC_BLOCKS + KA1_BLOCKS) {
        int blk = blockIdx.x - KC_BLOCKS;
        int b = blk / A_BLOCKS, ca = blk % A_BLOCKS;
        int a = ca * 256 + tid;
        __shared__ float4 gco[GG];             // x1,y1,x2,y2
        __shared__ float gar[GG];
        if (tid < GG) {
            float4 gb = ((const float4*)gt_boxes)[b * GG + tid];
            float x1 = gb.x - gb.z / 2.0f, y1 = gb.y - gb.w / 2.0f;
            float x2 = gb.x + gb.z / 2.0f, y2 = gb.y + gb.w / 2.0f;
            gco[tid] = make_float4(x1, y1, x2, y2);
            gar[tid] = (x2 - x1) * (y2 - y1);  // same rounding as reference
        }
        __syncthreads();
        if (a >= AA) return;
        float4 an = ((const float4*)anchors)[a];
        float ax1 = an.x - an.z / 2.0f, ay1 = an.y - an.w / 2.0f;
        float ax2 = an.x + an.z / 2.0f, ay2 = an.y + an.w / 2.0f;
        float aar = (ax2 - ax1) * (ay2 - ay1);
        float bi = -1.0f, bu = 1.0f; int bgi = 0;  // first compare always takes g=0
#pragma unroll
        for (int g = 0; g < GG; ++g) {
            float4 c = gco[g];
            float ltx = fmaxf(c.x, ax1), lty = fmaxf(c.y, ay1);
            float rbx = fminf(c.z, ax2), rby = fminf(c.w, ay2);
            float w = fmaxf(rbx - ltx, 0.0f), h = fmaxf(rby - lty, 0.0f);
            float inter = w * h;
            float uni = gar[g] + aar - inter;
            if (inter * bu > bi * uni) { bi = inter; bu = uni; bgi = g; }  // strict >: first max
        }
        bestg[b * AA + a] = (2.0f * bi > bu) ? (unsigned char)bgi : (unsigned char)0xFF;
    } else {
        int wv = tid >> 6, lane = tid & 63;
        int pair = (blockIdx.x - KC_BLOCKS - KA1_BLOCKS) * 4 + wv;  // 0..2047
        int b = pair >> 5, g = pair & 31;
        float4 gb = ((const float4*)gt_boxes)[b * GG + g];
        float gx1 = gb.x - gb.z / 2.0f, gy1 = gb.y - gb.w / 2.0f;
        float gx2 = gb.x + gb.z / 2.0f, gy2 = gb.y + gb.w / 2.0f;
        float gar = (gx2 - gx1) * (gy2 - gy1);
        float bi = -1.0f, bu = 1.0f; int ba = 0;
        for (int a = lane; a < AA; a += 64) {
            float4 an = ((const float4*)anchors)[a];
            float ax1 = an.x - an.z / 2.0f, ay1 = an.y - an.w / 2.0f;
            float ax2 = an.x + an.z / 2.0f, ay2 = an.y + an.w / 2.0f;
            float aar = (ax2 - ax1) * (ay2 - ay1);
            float ltx = fmaxf(gx1, ax1), lty = fmaxf(gy1, ay1);
            float rbx = fminf(gx2, ax2), rby = fminf(gy2, ay2);
            float w = fmaxf(rbx - ltx, 0.0f), h = fmaxf(rby - lty, 0.0f);
            float inter = w * h;
            float uni = gar + aar - inter;
            if (inter * bu > bi * uni) { bi = inter; bu = uni; ba = a; }  // smallest a in stream
        }
        // wave butterfly-reduce, lexicographic (iou desc, a asc)
#pragma unroll
        for (int off = 32; off > 0; off >>= 1) {
            float oi = __shfl_down(bi, off);
            float ou = __shfl_down(bu, off);
            int   oa = __shfl_down(ba, off);
            float p1 = oi * bu, p2 = bi * ou;
            bool take = (p1 > p2) || ((p1 == p2) && (oa < ba));
            if (take) { bi = oi; bu = ou; ba = oa; }
        }
        if (lane == 0) bestp[pair] = (unsigned int)ba;
    }
}

// ---------------- Kernel B: forced override (last g wins), labels, loc loss ----------------
__global__ __launch_bounds__(256) void kB_finalize(const float* __restrict__ anchors,
    const float* __restrict__ gt_boxes, const int* __restrict__ gt_labels,
    const float* __restrict__ loc_pred,
    const unsigned char* __restrict__ bestg,
    const unsigned int* __restrict__ bestp,
    unsigned char* __restrict__ label_out,
    int* __restrict__ num_pos, double* __restrict__ loc_sum,
    unsigned int* __restrict__ ticket, double* __restrict__ btot_acc,
    int* __restrict__ np_acc)
{
    int b = blockIdx.x, tid = threadIdx.x;
    if (b == 0 && tid == 0) { *ticket = 0u; *btot_acc = 0.0; *np_acc = 0; }  // for fused kDE
    __shared__ int forced[AA];                 // 34928 B
    __shared__ float gcx[GG], gcy[GG], gw[GG], gh[GG];
    __shared__ int glab[GG];
    __shared__ double red_d[256];
    __shared__ int red_i[256];

    for (int i = tid; i < AA; i += 256) forced[i] = -1;
    if (tid < GG) {
        float4 gb = ((const float4*)gt_boxes)[b * GG + tid];
        gcx[tid] = gb.x; gcy[tid] = gb.y; gw[tid] = gb.z; gh[tid] = gb.w;
        glab[tid] = gt_labels[b * GG + tid];
    }
    __syncthreads();
    if (tid < GG) {
        int besta = (int)bestp[b * GG + tid];
        atomicMax(&forced[besta], tid);        // duplicate anchors: largest g = last write wins
    }
    __syncthreads();

    double lsum = 0.0; int pcount = 0;
    for (int a = tid; a < AA; a += 256) {
        int gf = forced[a];
        int gsel;
        if (gf >= 0) gsel = gf;
        else {
            unsigned char bg = bestg[b * AA + a];
            gsel = (bg == 0xFF) ? -1 : (int)bg;
        }
        int lab = 0;
        if (gsel >= 0) {
            lab = glab[gsel];                  // labels in 1..C-1 -> always positive
            float4 an = ((const float4*)anchors)[a];
            float e0 = (gcx[gsel] - an.x) / an.z;
            float e1 = (gcy[gsel] - an.y) / an.w;
            float e2 = logf(gw[gsel]) - logf(an.z);
            float e3 = logf(gh[gsel]) - logf(an.w);
            float4 lp = ((const float4*)loc_pred)[b * AA + a];
            float d0 = lp.x - e0, d1 = lp.y - e1, d2 = lp.z - e2, d3 = lp.w - e3;
            float t = 0.0f, ad;
            ad = fabsf(d0); t += (ad < 1.0f) ? 0.5f * d0 * d0 : ad - 0.5f;
            ad = fabsf(d1); t += (ad < 1.0f) ? 0.5f * d1 * d1 : ad - 0.5f;
            ad = fabsf(d2); t += (ad < 1.0f) ? 0.5f * d2 * d2 : ad - 0.5f;
            ad = fabsf(d3); t += (ad < 1.0f) ? 0.5f * d3 * d3 : ad - 0.5f;
            lsum += (double)t;
            pcount++;
        }
        label_out[b * AA + a] = (unsigned char)lab;
    }
    red_d[tid] = lsum; red_i[tid] = pcount;
    __syncthreads();
    for (int s = 128; s > 0; s >>= 1) {
        if (tid < s) { red_d[tid] += red_d[tid + s]; red_i[tid] += red_i[tid + s]; }
        __syncthreads();
    }
    if (tid == 0) { num_pos[b] = red_i[0]; loc_sum[b] = red_d[0]; }
}

// ---------------- Kernel DE: radix-select top-k + positive CE + fused final reduce ----------------
__global__ __launch_bounds__(256) void kDE_select(const float* __restrict__ cls_l,
    const unsigned char* __restrict__ label, const float* __restrict__ conf,
    const int* __restrict__ num_pos, const double* __restrict__ loc_sum,
    unsigned int* __restrict__ ticket, double* __restrict__ btot_acc,
    int* __restrict__ np_acc, float* __restrict__ out)
{
    int b = blockIdx.x, tid = threadIdx.x;
    __shared__ unsigned int cl[AA];            // 34928 B (values clamped >= 0 -> bits monotone)
    __shared__ unsigned int hist[256];
    __shared__ unsigned int sh_prefix, sh_remaining;
    __shared__ double red_d[256];
    __shared__ unsigned int red_u[256];
    __shared__ double sh_pos;

    const float* src = cls_l + b * AA;
    const unsigned char* lb = label + b * AA;
    double pc = 0.0;
    for (int i = tid; i < AA; i += 256) {
        int lab = lb[i];
        float v = fmaxf(src[i], 0.0f);         // guard tiny negative lse-row0 rounding
        if (lab > 0) {
            size_t rowb = (size_t)(b * AA + i) * 81;
            pc += (double)(src[i] + conf[rowb] - conf[rowb + lab]);
            cl[i] = 0u;                        // positives excluded from neg mining
        } else {
            cl[i] = __float_as_uint(v);
        }
    }
    red_d[tid] = pc;
    __syncthreads();
    for (int s = 128; s > 0; s >>= 1) {
        if (tid < s) red_d[tid] += red_d[tid + s];
        __syncthreads();
    }
    if (tid == 0) sh_pos = red_d[0];

    int np_ = num_pos[b];
    int k = min(3 * np_, AA - 1);              // num_neg = min(3*num_pos, A-1)
    double topk = 0.0;
    int p_t_pos = 0;                           // positives inside neg_mask (tie at 0)
    if (tid == 0) { sh_prefix = 0u; sh_remaining = (unsigned int)k; }
    __syncthreads();

    if (k > 0) {
        for (int shift = 24; shift >= 0; shift -= 8) {
            hist[tid] = 0u;
            __syncthreads();
            unsigned int mask = (shift == 24) ? 0u : (0xFFFFFFFFu << (shift + 8));
            unsigned int pre = sh_prefix;
            for (int i = tid; i < AA; i += 256) {
                unsigned int u = cl[i];
                if ((u & mask) == pre) atomicAdd(&hist[(u >> shift) & 255], 1u);
            }
            __syncthreads();
            if (tid < 64) {                    // wave-parallel digit select
                int l = tid;
                unsigned int h4 = hist[4 * l] + hist[4 * l + 1]
                                + hist[4 * l + 2] + hist[4 * l + 3];
                unsigned int S = h4;           // suffix sum over lane groups
#pragma unroll
                for (int off = 1; off < 64; off <<= 1) {
                    unsigned int o = __shfl_down(S, off);
                    S += (l + off < 64) ? o : 0u;
                }
                unsigned int rem = sh_remaining;
                unsigned long long ball = __ballot(S >= rem);  // lanes 0..L set
                int L = 63 - __clzll(ball);
                if (l == L) {
                    unsigned int rem2 = rem - (S - h4);
                    unsigned int c = 0;
                    for (int dd = 4 * L + 3; dd >= 4 * L; --dd) {
                        c += hist[dd];
                        if (c >= rem2) {
                            sh_prefix = pre | ((unsigned int)dd << shift);
                            sh_remaining = rem2 - (c - hist[dd]);
                            break;
                        }
                    }
                }
            }
            __syncthreads();
        }
        unsigned int vbits = sh_prefix;
        unsigned int myc = 0; double mys = 0.0;
        for (int i = tid; i < AA; i += 256) {
            unsigned int u = cl[i];
            if (u > vbits) { myc++; mys += (double)__uint_as_float(u); }
        }
        red_u[tid] = myc; red_d[tid] = mys;
        __syncthreads();
        for (int s2 = 128; s2 > 0; s2 >>= 1) {
            if (tid < s2) { red_u[tid] += red_u[tid + s2]; red_d[tid] += red_d[tid + s2]; }
            __syncthreads();
        }
        int cnt_gt = (int)red_u[0];
        double sum_gt = red_d[0];
        topk = sum_gt + (double)(k - cnt_gt) * (double)__uint_as_float(vbits);
        if (tid == 0 && vbits == 0u) {
            int t = k - cnt_gt, c2 = 0;
            for (int i = 0; i < AA && c2 < t; ++i) {
                if (cl[i] == 0u) { c2++; if (lb[i] > 0) p_t_pos++; }
            }
        }
    }
    if (tid == 0) {
        int unsampled = AA - np_ - k + p_t_pos;
        double clsb = sh_pos + topk + (double)unsampled * (double)logf(81.0f);
        double myb = loc_sum[b] + clsb;
        atomicAdd(btot_acc, myb);              // device-scope by default
        atomicAdd(np_acc, np_);
        __threadfence();
        unsigned int t = atomicAdd(ticket, 1u);
        if (t == BB - 1) {                     // last block: all adds happened-before
            double tt = atomicAdd(btot_acc, 0.0);   // returns old = full sum
            int nn = atomicAdd(np_acc, 0);
            out[0] = (float)(tt / (double)nn);
        }
    }
}

extern "C" void kernel_launch(void* const* d_in, const int* in_sizes, int n_in,
                              void* d_out, int out_size, void* d_ws, size_t ws_size,
                              hipStream_t stream) {
    (void)in_sizes; (void)n_in; (void)out_size; (void)ws_size;
    const float* loc_pred  = (const float*)d_in[0];
    const float* conf_pred = (const float*)d_in[1];
    const float* anchors   = (const float*)d_in[2];
    const float* gt_boxes  = (const float*)d_in[3];
    const int*   gt_labels = (const int*)d_in[4];

    char* ws = (char*)d_ws;
    unsigned int*  bestp    = (unsigned int*)(ws + 0);
    unsigned char* bestg    = (unsigned char*)(ws + 16640);
    unsigned char* label    = (unsigned char*)(ws + 575488);
    float*         cls_l    = (float*)(ws + 1134336);
    int*           num_pos  = (int*)(ws + 3369728);
    double*        loc_sum  = (double*)(ws + 3369984);
    unsigned int*  ticket   = (unsigned int*)(ws + 3370496);
    double*        btot_acc = (double*)(ws + 3370504);
    int*           np_acc   = (int*)(ws + 3370512);

    kAC       <<<KC_BLOCKS + KA1_BLOCKS + KA2_BLOCKS, 256, 0, stream>>>(
        anchors, gt_boxes, conf_pred, bestg, bestp, cls_l);
    kB_finalize<<<BB, 256, 0, stream>>>(anchors, gt_boxes, gt_labels, loc_pred,
        bestg, bestp, label, num_pos, loc_sum, ticket, btot_acc, np_acc);
    kDE_select<<<BB, 256, 0, stream>>>(cls_l, label, conf_pred, num_pos, loc_sum,
        ticket, btot_acc, np_acc, (float*)d_out);
}